// Round 6
// baseline (162.867 us; speedup 1.0000x reference)
//
#include <hip/hip_runtime.h>
#include <hip/hip_bf16.h>

// CoarsenLattice forward: out[Nc,128] = gather(fine, nbr)[Nc, 9*64] @ W[576,128]
// Round 6: pre-convert the fine table to bf16 (numerically identical to the
// in-kernel f2bf we already do). Halves the random-gather bytes and makes the
// 128 MB table fully L3-resident -> gather phase served from Infinity Cache.
// Conversion pass uses NT loads (fp32 stream must not evict the bf16 lines).
// Fallback to the round-5 fp32-gather kernel if ws_size is insufficient.

#define N_FINE   1048576
#define N_COARSE 262144
#define VAL_DIM  64
#define FE       9
#define NF       128
#define BM       128              // 8 waves * 16 rows
#define THREADS  512

typedef __attribute__((ext_vector_type(8))) short bf16x8;
typedef __attribute__((ext_vector_type(4))) float f32x4;
typedef __attribute__((ext_vector_type(4))) unsigned int u32x4;

__device__ __forceinline__ unsigned short f2bf(float f) {
    unsigned u = __float_as_uint(f);
    return (unsigned short)((u + 0x7FFFu + ((u >> 16) & 1u)) >> 16);
}

// ---- W prep: FE tiles of 8192 ushorts; byte stream = swizzled LDS image ----
__global__ void prep_wt_kernel(const float* __restrict__ w,
                               unsigned short* __restrict__ wTswz) {
    int i = blockIdx.x * 256 + threadIdx.x;
    if (i >= FE * 8192) return;
    int fe   = i >> 13;
    int r    = i & 8191;
    int byte = r * 2;
    int col  = byte >> 7;
    int b0   = (byte & 127) ^ ((col & 7) << 4);
    int k    = fe * 64 + (b0 >> 1);
    wTswz[i] = f2bf(w[(size_t)k * NF + col]);
}

// ---- table conversion: fp32[1M][64] -> bf16[1M][64], streaming ----
__global__ void conv_table_kernel(const float* __restrict__ fine,
                                  unsigned short* __restrict__ fineb) {
    // 64M floats = 8M chunks of 8; 524288 threads x 16 iters
    size_t i = (size_t)blockIdx.x * 256 + threadIdx.x;
    for (; i < (size_t)N_FINE * VAL_DIM / 8; i += 2048 * 256) {
        const f32x4* p = (const f32x4*)(fine + i * 8);
        f32x4 a = __builtin_nontemporal_load(p);
        f32x4 b = __builtin_nontemporal_load(p + 1);
        union { unsigned short u[8]; u32x4 v; } r;
        r.u[0] = f2bf(a.x); r.u[1] = f2bf(a.y); r.u[2] = f2bf(a.z); r.u[3] = f2bf(a.w);
        r.u[4] = f2bf(b.x); r.u[5] = f2bf(b.y); r.u[6] = f2bf(b.z); r.u[7] = f2bf(b.w);
        *(u32x4*)(fineb + i * 8) = r.v;   // regular store -> L3-allocated
    }
}

// ---- main kernel, bf16 gather (A-fragments load directly, no conversion) ----
__launch_bounds__(THREADS, 4)
__global__ void coarsen_bf16_kernel(const unsigned short* __restrict__ fineb,
                                    const int* __restrict__ nbr,
                                    const unsigned short* __restrict__ wTswz,
                                    float* __restrict__ out) {
    __shared__ __align__(16) unsigned short sW[2][8192];

    const int t    = threadIdx.x;
    const int wave = t >> 6;
    const int lane = t & 63;
    const int l15  = lane & 15;
    const int lhi  = lane >> 4;
    const int bRow = blockIdx.x * BM;
    const int myRow = bRow + wave * 16 + l15;

    int idx[FE];
    {
        const int* nb = nbr + (size_t)myRow * FE;
#pragma unroll
        for (int f = 0; f < FE; ++f) idx[f] = __builtin_nontemporal_load(nb + f);
    }

    f32x4 acc[8];
#pragma unroll
    for (int i = 0; i < 8; ++i) acc[i] = (f32x4)0.0f;

    bf16x8 a0[2], a1[2];   // double-buffered A fragments (ks=0 / ks=1)

#define LOAD_A(fe_, buf_) do {                                              \
    const char* rp_ = (const char*)fineb + (size_t)idx[fe_] * 128 + lhi * 16;\
    a0[buf_] = *(const bf16x8*)(rp_);                                       \
    a1[buf_] = *(const bf16x8*)(rp_ + 64);                                  \
} while (0)

#define STAGE_W(fe_, buf_) do {                                             \
    const char* gs_ = (const char*)wTswz + (size_t)(fe_) * 16384;           \
    char* ls_ = (char*)&sW[buf_][0];                                        \
    __builtin_amdgcn_global_load_lds(                                       \
        (const __attribute__((address_space(1))) void*)(gs_ + t * 16),      \
        (__attribute__((address_space(3))) void*)(ls_ + t * 16), 16, 0, 0); \
    __builtin_amdgcn_global_load_lds(                                       \
        (const __attribute__((address_space(1))) void*)(gs_ + 8192 + t * 16), \
        (__attribute__((address_space(3))) void*)(ls_ + 8192 + t * 16), 16, 0, 0); \
} while (0)

    STAGE_W(0, 0);
    LOAD_A(0, 0);
    asm volatile("s_waitcnt vmcnt(0)" ::: "memory");
    __syncthreads();

#pragma unroll
    for (int fe = 0; fe < FE; ++fe) {
        const int buf = fe & 1;
        if (fe + 1 < FE) {
            STAGE_W(fe + 1, buf ^ 1);      // 2 glds first (oldest in queue)
            LOAD_A(fe + 1, buf ^ 1);       // 2 A-loads stay in flight
        }
#pragma unroll
        for (int ks = 0; ks < 2; ++ks) {
            const bf16x8 a = ks ? a1[buf] : a0[buf];
            const int off = ks * 64 + lhi * 16;
#pragma unroll
            for (int fn = 0; fn < 8; ++fn) {
                const int col = fn * 16 + l15;
                const bf16x8 b = *(const bf16x8*)(
                    (const char*)&sW[buf][0] + col * 128 + (off ^ ((col & 7) << 4)));
                acc[fn] = __builtin_amdgcn_mfma_f32_16x16x32_bf16(a, b, acc[fn], 0, 0, 0);
            }
        }
        if (fe + 1 < FE) {
            asm volatile("s_waitcnt vmcnt(2)" ::: "memory");  // drain W stage, keep A
            __syncthreads();
        }
    }

#pragma unroll
    for (int fn = 0; fn < 8; ++fn)
#pragma unroll
        for (int j = 0; j < 4; ++j) {
            const int row = bRow + wave * 16 + lhi * 4 + j;
            const int col = fn * 16 + l15;
            __builtin_nontemporal_store(acc[fn][j], out + (size_t)row * NF + col);
        }
#undef LOAD_A
#undef STAGE_W
}

// ---- fallback: round-5 fp32-gather kernel (used if ws too small) ----
__launch_bounds__(THREADS, 4)
__global__ void coarsen_fp32_kernel(const float* __restrict__ fine,
                                    const int* __restrict__ nbr,
                                    const unsigned short* __restrict__ wTswz,
                                    float* __restrict__ out) {
    __shared__ __align__(16) unsigned short sW[2][8192];
    const int t    = threadIdx.x;
    const int wave = t >> 6;
    const int lane = t & 63;
    const int l15  = lane & 15;
    const int lhi  = lane >> 4;
    const int bRow = blockIdx.x * BM;
    const int myRow = bRow + wave * 16 + l15;

    int idx[FE];
    {
        const int* nb = nbr + (size_t)myRow * FE;
#pragma unroll
        for (int f = 0; f < FE; ++f) idx[f] = __builtin_nontemporal_load(nb + f);
    }
    f32x4 acc[8];
#pragma unroll
    for (int i = 0; i < 8; ++i) acc[i] = (f32x4)0.0f;
    float4 pa[4];
    bf16x8 af0, af1;

#define LOAD_A(fe_) do {                                                   \
    const float* rp_ = fine + (size_t)idx[fe_] * VAL_DIM + lhi * 8;        \
    pa[0] = *(const float4*)(rp_);                                         \
    pa[1] = *(const float4*)(rp_ + 4);                                     \
    pa[2] = *(const float4*)(rp_ + 32);                                    \
    pa[3] = *(const float4*)(rp_ + 36);                                    \
} while (0)
#define STAGE_W(fe_, buf_) do {                                            \
    const char* gs_ = (const char*)wTswz + (size_t)(fe_) * 16384;          \
    char* ls_ = (char*)&sW[buf_][0];                                       \
    __builtin_amdgcn_global_load_lds(                                      \
        (const __attribute__((address_space(1))) void*)(gs_ + t * 16),     \
        (__attribute__((address_space(3))) void*)(ls_ + t * 16), 16, 0, 0);\
    __builtin_amdgcn_global_load_lds(                                      \
        (const __attribute__((address_space(1))) void*)(gs_ + 8192 + t * 16), \
        (__attribute__((address_space(3))) void*)(ls_ + 8192 + t * 16), 16, 0, 0); \
} while (0)
#define CONV_A() do {                                                      \
    union { bf16x8 v; unsigned short u[8]; } c0_, c1_;                     \
    c0_.u[0] = f2bf(pa[0].x); c0_.u[1] = f2bf(pa[0].y);                    \
    c0_.u[2] = f2bf(pa[0].z); c0_.u[3] = f2bf(pa[0].w);                    \
    c0_.u[4] = f2bf(pa[1].x); c0_.u[5] = f2bf(pa[1].y);                    \
    c0_.u[6] = f2bf(pa[1].z); c0_.u[7] = f2bf(pa[1].w);                    \
    c1_.u[0] = f2bf(pa[2].x); c1_.u[1] = f2bf(pa[2].y);                    \
    c1_.u[2] = f2bf(pa[2].z); c1_.u[3] = f2bf(pa[2].w);                    \
    c1_.u[4] = f2bf(pa[3].x); c1_.u[5] = f2bf(pa[3].y);                    \
    c1_.u[6] = f2bf(pa[3].z); c1_.u[7] = f2bf(pa[3].w);                    \
    af0 = c0_.v; af1 = c1_.v;                                              \
} while (0)

    STAGE_W(0, 0);
    LOAD_A(0);
    asm volatile("s_waitcnt vmcnt(0)" ::: "memory");
    __syncthreads();
#pragma unroll
    for (int fe = 0; fe < FE; ++fe) {
        const int buf = fe & 1;
        CONV_A();
        if (fe + 1 < FE) { STAGE_W(fe + 1, buf ^ 1); LOAD_A(fe + 1); }
#pragma unroll
        for (int ks = 0; ks < 2; ++ks) {
            const bf16x8 a = ks ? af1 : af0;
            const int off = ks * 64 + lhi * 16;
#pragma unroll
            for (int fn = 0; fn < 8; ++fn) {
                const int col = fn * 16 + l15;
                const bf16x8 b = *(const bf16x8*)(
                    (const char*)&sW[buf][0] + col * 128 + (off ^ ((col & 7) << 4)));
                acc[fn] = __builtin_amdgcn_mfma_f32_16x16x32_bf16(a, b, acc[fn], 0, 0, 0);
            }
        }
        if (fe + 1 < FE) {
            asm volatile("s_waitcnt vmcnt(4)" ::: "memory");
            __syncthreads();
        }
    }
#pragma unroll
    for (int fn = 0; fn < 8; ++fn)
#pragma unroll
        for (int j = 0; j < 4; ++j) {
            const int row = bRow + wave * 16 + lhi * 4 + j;
            const int col = fn * 16 + l15;
            __builtin_nontemporal_store(acc[fn][j], out + (size_t)row * NF + col);
        }
#undef LOAD_A
#undef STAGE_W
#undef CONV_A
}

extern "C" void kernel_launch(void* const* d_in, const int* in_sizes, int n_in,
                              void* d_out, int out_size, void* d_ws, size_t ws_size,
                              hipStream_t stream) {
    const float* fine = (const float*)d_in[0];
    const int*   nbr  = (const int*)d_in[1];
    const float* w    = (const float*)d_in[2];
    float* out = (float*)d_out;

    unsigned short* wTswz = (unsigned short*)d_ws;            // 144 KB
    const size_t tblOff = 256 * 1024;                         // aligned region
    const size_t needed = tblOff + (size_t)N_FINE * VAL_DIM * 2;  // +128 MB

    prep_wt_kernel<<<(FE * 8192 + 255) / 256, 256, 0, stream>>>(w, wTswz);

    if (ws_size >= needed) {
        unsigned short* fineb = (unsigned short*)((char*)d_ws + tblOff);
        conv_table_kernel<<<2048, 256, 0, stream>>>(fine, fineb);
        coarsen_bf16_kernel<<<N_COARSE / BM, THREADS, 0, stream>>>(fineb, nbr, wTswz, out);
    } else {
        coarsen_fp32_kernel<<<N_COARSE / BM, THREADS, 0, stream>>>(fine, nbr, wTswz, out);
    }
}

// Round 7
// 159.501 us; speedup vs baseline: 1.0211x; 1.0211x over previous
//
#include <hip/hip_runtime.h>
#include <hip/hip_bf16.h>

// CoarsenLattice forward: out[Nc,128] = gather(fine, nbr)[Nc, 9*64] @ W[576,128]
// Round 7: Path B v2. conv+prep fused (NT fp32 reads, L3-allocating bf16
// writes); main bf16-gather kernel with distance-2 A prefetch (4 loads in
// flight per lane, counted vmcnt keeps them riding across barriers).

#define N_FINE   1048576
#define N_COARSE 262144
#define VAL_DIM  64
#define FE       9
#define NF       128
#define BM       128              // 8 waves * 16 rows
#define THREADS  512

typedef __attribute__((ext_vector_type(8))) short bf16x8;
typedef __attribute__((ext_vector_type(4))) float f32x4;
typedef __attribute__((ext_vector_type(4))) unsigned int u32x4;

__device__ __forceinline__ unsigned short f2bf(float f) {
    unsigned u = __float_as_uint(f);
    return (unsigned short)((u + 0x7FFFu + ((u >> 16) & 1u)) >> 16);
}

// ---- fused prep: W swizzle + table fp32->bf16 conversion ----
// wTswz: FE tiles of 8192 ushorts; byte stream = swizzled LDS image.
// fineb: bf16[1M][64]; NT fp32 reads, regular stores (L3-allocate).
__global__ void conv_prep_kernel(const float* __restrict__ fine,
                                 const float* __restrict__ w,
                                 unsigned short* __restrict__ fineb,
                                 unsigned short* __restrict__ wTswz) {
    const size_t tid = (size_t)blockIdx.x * 256 + threadIdx.x;   // 4096*256 = 1M

    if (tid < FE * 8192) {
        int i    = (int)tid;
        int fe   = i >> 13;
        int r    = i & 8191;
        int byte = r * 2;
        int col  = byte >> 7;
        int b0   = (byte & 127) ^ ((col & 7) << 4);
        int k    = fe * 64 + (b0 >> 1);
        wTswz[i] = f2bf(w[(size_t)k * NF + col]);
    }

    // 8M octets of 8 floats; 1M threads x 8 iters
    for (size_t i = tid; i < (size_t)N_FINE * VAL_DIM / 8; i += (size_t)4096 * 256) {
        const f32x4* p = (const f32x4*)(fine + i * 8);
        f32x4 a = __builtin_nontemporal_load(p);
        f32x4 b = __builtin_nontemporal_load(p + 1);
        union { unsigned short u[8]; u32x4 v; } r;
        r.u[0] = f2bf(a.x); r.u[1] = f2bf(a.y); r.u[2] = f2bf(a.z); r.u[3] = f2bf(a.w);
        r.u[4] = f2bf(b.x); r.u[5] = f2bf(b.y); r.u[6] = f2bf(b.z); r.u[7] = f2bf(b.w);
        *(u32x4*)(fineb + i * 8) = r.v;   // regular store -> L3-resident table
    }
}

// ---- main kernel: bf16 gather, distance-2 A prefetch ----
__launch_bounds__(THREADS, 4)
__global__ void coarsen_bf16_kernel(const unsigned short* __restrict__ fineb,
                                    const int* __restrict__ nbr,
                                    const unsigned short* __restrict__ wTswz,
                                    float* __restrict__ out) {
    __shared__ __align__(16) unsigned short sW[2][8192];

    const int t    = threadIdx.x;
    const int wave = t >> 6;
    const int lane = t & 63;
    const int l15  = lane & 15;
    const int lhi  = lane >> 4;
    const int bRow = blockIdx.x * BM;
    const int myRow = bRow + wave * 16 + l15;

    int idx[FE];
    {
        const int* nb = nbr + (size_t)myRow * FE;
#pragma unroll
        for (int f = 0; f < FE; ++f) idx[f] = __builtin_nontemporal_load(nb + f);
    }

    f32x4 acc[8];
#pragma unroll
    for (int i = 0; i < 8; ++i) acc[i] = (f32x4)0.0f;

    bf16x8 A0[3], A1[3];   // A fragment slots, distance-2 pipeline

#define LOAD_A(fe_, s_) do {                                                \
    const char* rp_ = (const char*)fineb + (size_t)idx[fe_] * 128 + lhi * 16;\
    A0[s_] = *(const bf16x8*)(rp_);                                         \
    A1[s_] = *(const bf16x8*)(rp_ + 64);                                    \
} while (0)

#define STAGE_W(fe_, buf_) do {                                             \
    const char* gs_ = (const char*)wTswz + (size_t)(fe_) * 16384;           \
    char* ls_ = (char*)&sW[buf_][0];                                        \
    __builtin_amdgcn_global_load_lds(                                       \
        (const __attribute__((address_space(1))) void*)(gs_ + t * 16),      \
        (__attribute__((address_space(3))) void*)(ls_ + t * 16), 16, 0, 0); \
    __builtin_amdgcn_global_load_lds(                                       \
        (const __attribute__((address_space(1))) void*)(gs_ + 8192 + t * 16), \
        (__attribute__((address_space(3))) void*)(ls_ + 8192 + t * 16), 16, 0, 0); \
} while (0)

    // prologue: a(0), a(1) in flight, W0 staged
    STAGE_W(0, 0);
    LOAD_A(0, 0);
    LOAD_A(1, 1);
    asm volatile("s_waitcnt vmcnt(0)" ::: "memory");
    __syncthreads();

#pragma unroll
    for (int fe = 0; fe < FE; ++fe) {
        const int buf  = fe & 1;
        const int slot = fe % 3;
        if (fe + 1 < FE) STAGE_W(fe + 1, buf ^ 1);       // W glds first
        if (fe + 2 < FE) LOAD_A(fe + 2, (fe + 2) % 3);   // A gathers behind them

#pragma unroll
        for (int ks = 0; ks < 2; ++ks) {
            const bf16x8 a = ks ? A1[slot] : A0[slot];
            const int off = ks * 64 + lhi * 16;
#pragma unroll
            for (int fn = 0; fn < 8; ++fn) {
                const int col = fn * 16 + l15;
                const bf16x8 b = *(const bf16x8*)(
                    (const char*)&sW[buf][0] + col * 128 + (off ^ ((col & 7) << 4)));
                acc[fn] = __builtin_amdgcn_mfma_f32_16x16x32_bf16(a, b, acc[fn], 0, 0, 0);
            }
        }

        if (fe + 1 < FE) {
            // drain W(fe+1) (and the older a(fe+1)); keep a(fe+2) in flight
            if (fe + 2 < FE) asm volatile("s_waitcnt vmcnt(2)" ::: "memory");
            else             asm volatile("s_waitcnt vmcnt(0)" ::: "memory");
            __syncthreads();
        }
    }

#pragma unroll
    for (int fn = 0; fn < 8; ++fn)
#pragma unroll
        for (int j = 0; j < 4; ++j) {
            const int row = bRow + wave * 16 + lhi * 4 + j;
            const int col = fn * 16 + l15;
            __builtin_nontemporal_store(acc[fn][j], out + (size_t)row * NF + col);
        }
#undef LOAD_A
#undef STAGE_W
}

// ---- fallback: round-5 fp32-gather path (ws too small) ----
__global__ void prep_wt_kernel(const float* __restrict__ w,
                               unsigned short* __restrict__ wTswz) {
    int i = blockIdx.x * 256 + threadIdx.x;
    if (i >= FE * 8192) return;
    int fe   = i >> 13;
    int r    = i & 8191;
    int byte = r * 2;
    int col  = byte >> 7;
    int b0   = (byte & 127) ^ ((col & 7) << 4);
    int k    = fe * 64 + (b0 >> 1);
    wTswz[i] = f2bf(w[(size_t)k * NF + col]);
}

__launch_bounds__(THREADS, 4)
__global__ void coarsen_fp32_kernel(const float* __restrict__ fine,
                                    const int* __restrict__ nbr,
                                    const unsigned short* __restrict__ wTswz,
                                    float* __restrict__ out) {
    __shared__ __align__(16) unsigned short sW[2][8192];
    const int t    = threadIdx.x;
    const int wave = t >> 6;
    const int lane = t & 63;
    const int l15  = lane & 15;
    const int lhi  = lane >> 4;
    const int bRow = blockIdx.x * BM;
    const int myRow = bRow + wave * 16 + l15;

    int idx[FE];
    {
        const int* nb = nbr + (size_t)myRow * FE;
#pragma unroll
        for (int f = 0; f < FE; ++f) idx[f] = __builtin_nontemporal_load(nb + f);
    }
    f32x4 acc[8];
#pragma unroll
    for (int i = 0; i < 8; ++i) acc[i] = (f32x4)0.0f;
    float4 pa[4];
    bf16x8 af0, af1;

#define LOAD_A(fe_) do {                                                   \
    const float* rp_ = fine + (size_t)idx[fe_] * VAL_DIM + lhi * 8;        \
    pa[0] = *(const float4*)(rp_);                                         \
    pa[1] = *(const float4*)(rp_ + 4);                                     \
    pa[2] = *(const float4*)(rp_ + 32);                                    \
    pa[3] = *(const float4*)(rp_ + 36);                                    \
} while (0)
#define STAGE_W(fe_, buf_) do {                                            \
    const char* gs_ = (const char*)wTswz + (size_t)(fe_) * 16384;          \
    char* ls_ = (char*)&sW[buf_][0];                                       \
    __builtin_amdgcn_global_load_lds(                                      \
        (const __attribute__((address_space(1))) void*)(gs_ + t * 16),     \
        (__attribute__((address_space(3))) void*)(ls_ + t * 16), 16, 0, 0);\
    __builtin_amdgcn_global_load_lds(                                      \
        (const __attribute__((address_space(1))) void*)(gs_ + 8192 + t * 16), \
        (__attribute__((address_space(3))) void*)(ls_ + 8192 + t * 16), 16, 0, 0); \
} while (0)
#define CONV_A() do {                                                      \
    union { bf16x8 v; unsigned short u[8]; } c0_, c1_;                     \
    c0_.u[0] = f2bf(pa[0].x); c0_.u[1] = f2bf(pa[0].y);                    \
    c0_.u[2] = f2bf(pa[0].z); c0_.u[3] = f2bf(pa[0].w);                    \
    c0_.u[4] = f2bf(pa[1].x); c0_.u[5] = f2bf(pa[1].y);                    \
    c0_.u[6] = f2bf(pa[1].z); c0_.u[7] = f2bf(pa[1].w);                    \
    c1_.u[0] = f2bf(pa[2].x); c1_.u[1] = f2bf(pa[2].y);                    \
    c1_.u[2] = f2bf(pa[2].z); c1_.u[3] = f2bf(pa[2].w);                    \
    c1_.u[4] = f2bf(pa[3].x); c1_.u[5] = f2bf(pa[3].y);                    \
    c1_.u[6] = f2bf(pa[3].z); c1_.u[7] = f2bf(pa[3].w);                    \
    af0 = c0_.v; af1 = c1_.v;                                              \
} while (0)

    STAGE_W(0, 0);
    LOAD_A(0);
    asm volatile("s_waitcnt vmcnt(0)" ::: "memory");
    __syncthreads();
#pragma unroll
    for (int fe = 0; fe < FE; ++fe) {
        const int buf = fe & 1;
        CONV_A();
        if (fe + 1 < FE) { STAGE_W(fe + 1, buf ^ 1); LOAD_A(fe + 1); }
#pragma unroll
        for (int ks = 0; ks < 2; ++ks) {
            const bf16x8 a = ks ? af1 : af0;
            const int off = ks * 64 + lhi * 16;
#pragma unroll
            for (int fn = 0; fn < 8; ++fn) {
                const int col = fn * 16 + l15;
                const bf16x8 b = *(const bf16x8*)(
                    (const char*)&sW[buf][0] + col * 128 + (off ^ ((col & 7) << 4)));
                acc[fn] = __builtin_amdgcn_mfma_f32_16x16x32_bf16(a, b, acc[fn], 0, 0, 0);
            }
        }
        if (fe + 1 < FE) {
            asm volatile("s_waitcnt vmcnt(4)" ::: "memory");
            __syncthreads();
        }
    }
#pragma unroll
    for (int fn = 0; fn < 8; ++fn)
#pragma unroll
        for (int j = 0; j < 4; ++j) {
            const int row = bRow + wave * 16 + lhi * 4 + j;
            const int col = fn * 16 + l15;
            __builtin_nontemporal_store(acc[fn][j], out + (size_t)row * NF + col);
        }
#undef LOAD_A
#undef STAGE_W
#undef CONV_A
}

extern "C" void kernel_launch(void* const* d_in, const int* in_sizes, int n_in,
                              void* d_out, int out_size, void* d_ws, size_t ws_size,
                              hipStream_t stream) {
    const float* fine = (const float*)d_in[0];
    const int*   nbr  = (const int*)d_in[1];
    const float* w    = (const float*)d_in[2];
    float* out = (float*)d_out;

    unsigned short* wTswz = (unsigned short*)d_ws;            // 144 KB
    const size_t tblOff = 256 * 1024;
    const size_t needed = tblOff + (size_t)N_FINE * VAL_DIM * 2;  // +128 MB

    if (ws_size >= needed) {
        unsigned short* fineb = (unsigned short*)((char*)d_ws + tblOff);
        conv_prep_kernel<<<4096, 256, 0, stream>>>(fine, w, fineb, wTswz);
        coarsen_bf16_kernel<<<N_COARSE / BM, THREADS, 0, stream>>>(fineb, nbr, wTswz, out);
    } else {
        prep_wt_kernel<<<(FE * 8192 + 255) / 256, 256, 0, stream>>>(w, wTswz);
        coarsen_fp32_kernel<<<N_COARSE / BM, THREADS, 0, stream>>>(fine, nbr, wTswz, out);
    }
}

// Round 8
// 126.383 us; speedup vs baseline: 1.2887x; 1.2620x over previous
//
#include <hip/hip_runtime.h>
#include <hip/hip_bf16.h>

// CoarsenLattice forward: out[Nc,128] = gather(fine, nbr)[Nc, 9*64] @ W[576,128]
// FINAL (= round 5, best measured: 127.2 us). Reg-gathered A (wave owns 16
// rows), W staged per-fe via global_load_lds double-buffer, counted vmcnt
// keeps A-gathers in flight across the one barrier per fe, NT output stores.
// Rounds 2-7 established the ~2.6 TB/s random-256B-gather pattern ceiling;
// traffic is within 8% of compulsory, so this is the roofline structure.

#define N_FINE   1048576
#define N_COARSE 262144
#define VAL_DIM  64
#define FE       9
#define NF       128
#define BM       128              // 8 waves * 16 rows
#define THREADS  512

typedef __attribute__((ext_vector_type(8))) short bf16x8;
typedef __attribute__((ext_vector_type(4))) float f32x4;

__device__ __forceinline__ unsigned short f2bf(float f) {
    unsigned u = __float_as_uint(f);
    return (unsigned short)((u + 0x7FFFu + ((u >> 16) & 1u)) >> 16);
}

// W prep: wTswz is FE tiles of 8192 ushorts (16 KB). Byte stream is the LDS
// image: logical chunk (col,kc) lives at byte col*128 + ((kc*16)^((col&7)<<4)).
__global__ void prep_wt_kernel(const float* __restrict__ w,
                               unsigned short* __restrict__ wTswz) {
    int i = blockIdx.x * 256 + threadIdx.x;     // over FE*8192 = 73728 ushorts
    if (i >= FE * 8192) return;
    int fe   = i >> 13;
    int r    = i & 8191;
    int byte = r * 2;
    int col  = byte >> 7;                       // 0..127
    int b0   = (byte & 127) ^ ((col & 7) << 4); // unswizzled byte within row
    int k    = fe * 64 + (b0 >> 1);
    wTswz[i] = f2bf(w[(size_t)k * NF + col]);
}

__launch_bounds__(THREADS, 4)
__global__ void coarsen_kernel(const float* __restrict__ fine,
                               const int* __restrict__ nbr,
                               const unsigned short* __restrict__ wTswz,
                               float* __restrict__ out) {
    __shared__ __align__(16) unsigned short sW[2][8192];   // 2 x 16 KB

    const int t    = threadIdx.x;
    const int wave = t >> 6;
    const int lane = t & 63;
    const int l15  = lane & 15;
    const int lhi  = lane >> 4;
    const int bRow = blockIdx.x * BM;
    const int myRow = bRow + wave * 16 + l15;

    // hoist all 9 neighbor indices into registers (single-use stream: NT loads)
    int idx[FE];
    {
        const int* nb = nbr + (size_t)myRow * FE;
#pragma unroll
        for (int f = 0; f < FE; ++f) idx[f] = __builtin_nontemporal_load(nb + f);
    }

    f32x4 acc[8];
#pragma unroll
    for (int i = 0; i < 8; ++i) acc[i] = (f32x4)0.0f;

    float4 pa[4];        // prefetched A row chunk
    bf16x8 af0, af1;     // current A fragments (ks=0,1)

#define LOAD_A(fe_) do {                                                   \
    const float* rp_ = fine + (size_t)idx[fe_] * VAL_DIM + lhi * 8;        \
    pa[0] = *(const float4*)(rp_);                                         \
    pa[1] = *(const float4*)(rp_ + 4);                                     \
    pa[2] = *(const float4*)(rp_ + 32);                                    \
    pa[3] = *(const float4*)(rp_ + 36);                                    \
} while (0)

#define STAGE_W(fe_, buf_) do {                                            \
    const char* gs_ = (const char*)wTswz + (size_t)(fe_) * 16384;          \
    char* ls_ = (char*)&sW[buf_][0];                                       \
    __builtin_amdgcn_global_load_lds(                                      \
        (const __attribute__((address_space(1))) void*)(gs_ + t * 16),     \
        (__attribute__((address_space(3))) void*)(ls_ + t * 16), 16, 0, 0);\
    __builtin_amdgcn_global_load_lds(                                      \
        (const __attribute__((address_space(1))) void*)(gs_ + 8192 + t * 16), \
        (__attribute__((address_space(3))) void*)(ls_ + 8192 + t * 16), 16, 0, 0); \
} while (0)

#define CONV_A() do {                                                      \
    union { bf16x8 v; unsigned short u[8]; } c0_, c1_;                     \
    c0_.u[0] = f2bf(pa[0].x); c0_.u[1] = f2bf(pa[0].y);                    \
    c0_.u[2] = f2bf(pa[0].z); c0_.u[3] = f2bf(pa[0].w);                    \
    c0_.u[4] = f2bf(pa[1].x); c0_.u[5] = f2bf(pa[1].y);                    \
    c0_.u[6] = f2bf(pa[1].z); c0_.u[7] = f2bf(pa[1].w);                    \
    c1_.u[0] = f2bf(pa[2].x); c1_.u[1] = f2bf(pa[2].y);                    \
    c1_.u[2] = f2bf(pa[2].z); c1_.u[3] = f2bf(pa[2].w);                    \
    c1_.u[4] = f2bf(pa[3].x); c1_.u[5] = f2bf(pa[3].y);                    \
    c1_.u[6] = f2bf(pa[3].z); c1_.u[7] = f2bf(pa[3].w);                    \
    af0 = c0_.v; af1 = c1_.v;                                              \
} while (0)

    // ---- prologue: stage fe=0 ----
    STAGE_W(0, 0);
    LOAD_A(0);
    asm volatile("s_waitcnt vmcnt(0)" ::: "memory");
    __syncthreads();

#pragma unroll
    for (int fe = 0; fe < FE; ++fe) {
        const int buf = fe & 1;
        CONV_A();
        if (fe + 1 < FE) {
            STAGE_W(fe + 1, buf ^ 1);          // glds first (oldest in queue)
            LOAD_A(fe + 1);                    // A gathers stay in flight
        }
#pragma unroll
        for (int ks = 0; ks < 2; ++ks) {
            const bf16x8 a = ks ? af1 : af0;
            const int off = ks * 64 + lhi * 16;
#pragma unroll
            for (int fn = 0; fn < 8; ++fn) {
                const int col = fn * 16 + l15;
                const bf16x8 b = *(const bf16x8*)(
                    (const char*)&sW[buf][0] + col * 128 + (off ^ ((col & 7) << 4)));
                acc[fn] = __builtin_amdgcn_mfma_f32_16x16x32_bf16(a, b, acc[fn], 0, 0, 0);
            }
        }
        if (fe + 1 < FE) {
            asm volatile("s_waitcnt vmcnt(4)" ::: "memory");  // drain W stage only
            __syncthreads();
        }
    }

    // ---- epilogue: nontemporal stores (don't evict gather lines from L2/L3)
#pragma unroll
    for (int fn = 0; fn < 8; ++fn)
#pragma unroll
        for (int j = 0; j < 4; ++j) {
            const int row = bRow + wave * 16 + lhi * 4 + j;
            const int col = fn * 16 + l15;
            __builtin_nontemporal_store(acc[fn][j], out + (size_t)row * NF + col);
        }

#undef LOAD_A
#undef STAGE_W
#undef CONV_A
}

extern "C" void kernel_launch(void* const* d_in, const int* in_sizes, int n_in,
                              void* d_out, int out_size, void* d_ws, size_t ws_size,
                              hipStream_t stream) {
    const float* fine = (const float*)d_in[0];
    const int*   nbr  = (const int*)d_in[1];
    const float* w    = (const float*)d_in[2];
    float* out = (float*)d_out;

    unsigned short* wTswz = (unsigned short*)d_ws;   // FE*8192 ushorts = 144 KB

    prep_wt_kernel<<<(FE * 8192 + 255) / 256, 256, 0, stream>>>(w, wTswz);
    coarsen_kernel<<<N_COARSE / BM, THREADS, 0, stream>>>(fine, nbr, wTswz, out);
}